// Round 12
// baseline (65.279 us; speedup 1.0000x reference)
//
#include <hip/hip_runtime.h>
#include <hip/hip_bf16.h>
#include <math.h>

// CoSent clustering loss on MI355X — round 12.
// Label logic removed from the hot loop: main GEMM epilogue computes only
// T_row = sum_all exp(+s*sim) (3 VALU insts/element; scale folded into fp8
// quantization). Positive pairs (1/128 of elements) handled exactly by a
// per-label correction pass: member lists -> small per-label Gram via MFMA
// (bf16 row-major copy) -> A_g and P_g; finalize uses B_g = T_g - P_g.

typedef __attribute__((ext_vector_type(2))) long l2;     // two fp8 frags
typedef __attribute__((ext_vector_type(4))) float f32x4;
typedef __attribute__((ext_vector_type(8))) __bf16 bf16x8;

#define N_EMB 8192
#define D_EMB 256
#define NUM_LABELS 128
#define PAN 128
#define NPAN (N_EMB / PAN)           // 64
#define NTRI (NPAN * (NPAN + 1) / 2) // 2080 = 8 * 260
#define PCAP 192                     // per-label member cap (mean 64, sd 8)

// ---- DPP 16-lane reduction helpers ----
template <int CTRL>
__device__ __forceinline__ float dpp_add(float x) {
    int y = __builtin_amdgcn_update_dpp(0, __builtin_bit_cast(int, x),
                                        CTRL, 0xF, 0xF, false);
    return x + __builtin_bit_cast(float, y);
}
__device__ __forceinline__ float red16(float x) {
    x = dpp_add<0xB1>(x);    // quad_perm xor1
    x = dpp_add<0x4E>(x);    // quad_perm xor2
    x = dpp_add<0x124>(x);   // row_ror:4
    x = dpp_add<0x128>(x);   // row_ror:8
    return x;
}

__device__ __forceinline__ float exp2hw(float x) {
    float r;
    asm("v_exp_f32 %0, %1" : "=v"(r) : "v"(x));
    return r;
}

__device__ __forceinline__ unsigned packbf(float a, float b) {
    unsigned ua = __builtin_bit_cast(unsigned, a);
    unsigned ub = __builtin_bit_cast(unsigned, b);
    ua += 0x7FFFu + ((ua >> 16) & 1u);   // RTNE to bf16
    ub += 0x7FFFu + ((ub >> 16) & 1u);
    return (ua >> 16) | (ub & 0xFFFF0000u);
}

// ---------------------------------------------------------------- normalize
// Writes (a) fp8 superfrag-major e8 PRESCALED by sqrt(s*log2e) (so MFMA acc
// = s*log2e*sim directly), (b) bf16 row-major e16 (unscaled, for the
// correction Gram), and zeroes cnt[] (block 0).
__global__ __launch_bounds__(256) void normalize_kernel(const float* __restrict__ emb,
                                                        const float* __restrict__ scale,
                                                        char* __restrict__ e8,
                                                        unsigned* __restrict__ e16,
                                                        int* __restrict__ cnt) {
    const int wid = threadIdx.x >> 6, lane = threadIdx.x & 63;
    const int row = blockIdx.x * 4 + wid;
    const f32x4 x = *(const f32x4*)(emb + (size_t)row * D_EMB + lane * 4);
    float ss = x[0]*x[0] + x[1]*x[1] + x[2]*x[2] + x[3]*x[3];
    #pragma unroll
    for (int off = 32; off >= 1; off >>= 1) ss += __shfl_xor(ss, off);
    const float r = 1.0f / fmaxf(sqrtf(ss), 1e-12f);
    const float ps = sqrtf(scale[0] * 1.44269504088896f) * r;   // prescale

    // fp8 superfrag-major (see r10), values x*ps
    int v = __builtin_amdgcn_cvt_pk_fp8_f32(x[0] * ps, x[1] * ps, 0, false);
    v = __builtin_amdgcn_cvt_pk_fp8_f32(x[2] * ps, x[3] * ps, v, true);
    const int u    = lane >> 4;
    const int half = (lane >> 3) & 1;
    const int lp   = ((lane >> 1) & 3) * 16 + (row & 15);
    const int j0   = (lane & 1) * 4;
    char* dst = e8 + ((size_t)(row >> 4) * 4 + u) * 1024 + lp * 16 + half * 8 + j0;
    *(unsigned*)dst = (unsigned)v;

    // bf16 row-major (unscaled normalized)
    uint2 o = { packbf(x[0] * r, x[1] * r), packbf(x[2] * r, x[3] * r) };
    *(uint2*)((char*)e16 + (size_t)row * 512 + lane * 8) = o;

    if (blockIdx.x == 0 && threadIdx.x < NUM_LABELS) cnt[threadIdx.x] = 0;
}

// --------------------------------------------------------------- build lists
__global__ __launch_bounds__(256) void build_lists(const int* __restrict__ labels,
                                                   int* __restrict__ cnt,
                                                   int* __restrict__ perm) {
    const int i = blockIdx.x * 256 + threadIdx.x;
    const int g = labels[i];
    const int slot = atomicAdd(&cnt[g], 1);
    if (slot < PCAP) perm[g * PCAP + slot] = i;
}

// ---- pinned coalesced superfrag load: SGPR base + VGPR offset + literal ----
#define LOADF(dst, voff, sb, OFFSTR) \
    asm volatile("global_load_dwordx4 %0, %1, %2 offset:" OFFSTR \
                 : "=v"(dst) : "v"(voff), "s"(sb))

#define ISSUE(PA_, PB_, OFFSTR) \
    LOADF(PA_[0], voA[0], sbA, OFFSTR); LOADF(PA_[1], voA[1], sbA, OFFSTR); \
    LOADF(PA_[2], voA[2], sbA, OFFSTR); LOADF(PA_[3], voA[3], sbA, OFFSTR); \
    LOADF(PB_[0], voB[0], sbB, OFFSTR); LOADF(PB_[1], voB[1], sbB, OFFSTR); \
    LOADF(PB_[2], voB[2], sbB, OFFSTR); LOADF(PB_[3], voB[3], sbB, OFFSTR)

#define WAITV(NSTR) \
    asm volatile("s_waitcnt vmcnt(" NSTR ")" ::: "memory"); \
    __builtin_amdgcn_sched_barrier(0)

#define MF8(a, b, c) __builtin_amdgcn_mfma_f32_16x16x32_fp8_fp8(a, b, c, 0, 0, 0)

#define MROW(PA_, PB_, mi, H) \
    acc[mi][0] = MF8(PA_[mi][H], PB_[0][H], acc[mi][0]); \
    acc[mi][1] = MF8(PA_[mi][H], PB_[1][H], acc[mi][1]); \
    acc[mi][2] = MF8(PA_[mi][H], PB_[2][H], acc[mi][2]); \
    acc[mi][3] = MF8(PA_[mi][H], PB_[3][H], acc[mi][3]);

#define MFMA32(PA_, PB_) \
    __builtin_amdgcn_s_setprio(1); \
    MROW(PA_, PB_, 0, 0) MROW(PA_, PB_, 1, 0) MROW(PA_, PB_, 2, 0) MROW(PA_, PB_, 3, 0) \
    MROW(PA_, PB_, 0, 1) MROW(PA_, PB_, 1, 1) MROW(PA_, PB_, 2, 1) MROW(PA_, PB_, 3, 1) \
    __builtin_amdgcn_s_setprio(0)

// ------------------------------------------------------------- main (merged)
// Blocks 0..127: per-label correction (A_g, P_g via bf16 Gram).
// Blocks 128..: triangular 128x128 fp8 tile -> T partial rows/cols.
__global__ __launch_bounds__(256, 3) void cosent_main(const char* __restrict__ e8,
                                                      const __bf16* __restrict__ e16,
                                                      const int* __restrict__ perm,
                                                      const int* __restrict__ cnt,
                                                      const float* __restrict__ scale,
                                                      float* __restrict__ wsT,
                                                      float* __restrict__ Acorr,
                                                      float* __restrict__ Pcorr) {
    __shared__ float rowsc[2][PAN];
    __shared__ float colsc[2][PAN];
    __shared__ int ilist[PCAP];
    __shared__ float wredA[4], wredP[4];

    const int tid = threadIdx.x, lane = tid & 63, wid = tid >> 6;
    const int rr = lane & 15, kh = lane >> 4;

    if (blockIdx.x < NUM_LABELS) {
        // ---------------- correction path: label g -------------------------
        const int g = blockIdx.x;
        const int c = cnt[g];
        if (tid < c && tid < PCAP) ilist[tid] = perm[g * PCAP + tid];
        __syncthreads();
        const float s2 = scale[0] * 1.44269504088896f;
        const int nt = (c + 15) >> 4;
        float pa = 0.f, pp = 0.f;
        for (int tt = wid; tt < nt * nt; tt += 4) {
            const int ti = tt / nt, tj = tt - ti * nt;
            const int rloc = ti * 16 + rr, cloc = tj * 16 + rr;
            const int ridx = ilist[rloc < c ? rloc : 0];
            const int cidx = ilist[cloc < c ? cloc : 0];
            f32x4 a4 = (f32x4){0.f, 0.f, 0.f, 0.f};
            #pragma unroll
            for (int t = 0; t < 8; ++t) {
                const bf16x8 af = *(const bf16x8*)(e16 + (size_t)ridx * 256 + t * 32 + kh * 8);
                const bf16x8 bf = *(const bf16x8*)(e16 + (size_t)cidx * 256 + t * 32 + kh * 8);
                a4 = __builtin_amdgcn_mfma_f32_16x16x32_bf16(af, bf, a4, 0, 0, 0);
            }
            #pragma unroll
            for (int r = 0; r < 4; ++r) {
                const int rg = ti * 16 + kh * 4 + r;
                const int cg = tj * 16 + rr;
                const bool in = (rg < c) && (cg < c);
                const int rj = ilist[in ? rg : 0];
                const int rk = ilist[in ? cg : 0];
                const float v = a4[r] * s2;
                if (in && rj != rk) { pa += exp2hw(-v); pp += exp2hw(v); }
            }
        }
        #pragma unroll
        for (int off = 32; off >= 1; off >>= 1) {
            pa += __shfl_xor(pa, off);
            pp += __shfl_xor(pp, off);
        }
        if (lane == 0) { wredA[wid] = pa; wredP[wid] = pp; }
        __syncthreads();
        if (tid == 0) {
            Acorr[g] = wredA[0] + wredA[1] + wredA[2] + wredA[3];
            Pcorr[g] = wredP[0] + wredP[1] + wredP[2] + wredP[3];
        }
        return;
    }

    // ---------------- main GEMM path --------------------------------------
    const int bid = blockIdx.x - NUM_LABELS;
    const int swz = (bid & 7) * 260 + (bid >> 3);   // XCD-bijective (2080=8*260)
    int by = (int)((129.0f - sqrtf(16641.0f - 8.0f * (float)swz)) * 0.5f);
    by = by < 0 ? 0 : (by > 63 ? 63 : by);
    while (by < 63 && (by + 1) * (129 - (by + 1)) / 2 <= swz) ++by;
    while (by > 0 && by * (129 - by) / 2 > swz) --by;
    const int bx = by + (swz - by * (129 - by) / 2);
    const bool diag = (bx == by);
    const int rowBase = by * PAN, colBase = bx * PAN;

    const int wm = wid >> 1, wn = wid & 1;

    const int laneB = lane * 16;
    int voA[4], voB[4];
    #pragma unroll
    for (int i = 0; i < 4; ++i) {
        voA[i] = (wm * 4 + i) * 4096 + laneB;
        voB[i] = (wn * 4 + i) * 4096 + laneB;
    }
    const char* sbA = e8 + (size_t)rowBase * 256;
    const char* sbB = e8 + (size_t)colBase * 256;

    f32x4 acc[4][4];
    #pragma unroll
    for (int i = 0; i < 4; ++i)
        #pragma unroll
        for (int j = 0; j < 4; ++j) acc[i][j] = (f32x4){0.f, 0.f, 0.f, 0.f};

    l2 pA[4], pB[4], qA[4], qB[4];

    ISSUE(pA, pB, "0");                                   // u=0
    ISSUE(qA, qB, "1024"); WAITV("8"); MFMA32(pA, pB);    // u=1 | u0
    ISSUE(pA, pB, "2048"); WAITV("8"); MFMA32(qA, qB);    // u=2 | u1
    ISSUE(qA, qB, "3072"); WAITV("8"); MFMA32(pA, pB);    // u=3 | u2
    WAITV("0"); MFMA32(qA, qB);                           //     | u3

    // ---- lean epilogue: T only (acc is already s*log2e*sim) ----
    float colT[4] = {0.f, 0.f, 0.f, 0.f};
    if (!diag) {
        #pragma unroll
        for (int mi = 0; mi < 4; ++mi) {
            #pragma unroll
            for (int r = 0; r < 4; ++r) {
                float bs = 0.f;
                #pragma unroll
                for (int ni = 0; ni < 4; ++ni) {
                    const float ex = exp2hw(acc[mi][ni][r]);
                    bs += ex;
                    colT[ni] += ex;
                }
                bs = red16(bs);
                if (rr == 0) rowsc[wn][wm * 64 + mi * 16 + kh * 4 + r] = bs;
            }
        }
        #pragma unroll
        for (int ni = 0; ni < 4; ++ni) {
            float a = colT[ni];
            a += __shfl_xor(a, 16); a += __shfl_xor(a, 32);
            if (lane < 16) colsc[wm][wn * 64 + ni * 16 + lane] = a;
        }
    } else {
        #pragma unroll
        for (int mi = 0; mi < 4; ++mi) {
            #pragma unroll
            for (int r = 0; r < 4; ++r) {
                const int rowL = wm * 64 + mi * 16 + kh * 4 + r;
                float bs = 0.f;
                #pragma unroll
                for (int ni = 0; ni < 4; ++ni) {
                    float ex = exp2hw(acc[mi][ni][r]);
                    if (rowL == wn * 64 + ni * 16 + rr) ex = 0.f;   // self-pair
                    bs += ex;
                }
                bs = red16(bs);
                if (rr == 0) rowsc[wn][rowL] = bs;
            }
        }
    }
    __syncthreads();

    if (tid < PAN) {
        wsT[(size_t)bx * N_EMB + rowBase + tid] = rowsc[0][tid] + rowsc[1][tid];
        if (!diag)
            wsT[(size_t)by * N_EMB + colBase + tid] = colsc[0][tid] + colsc[1][tid];
    }
}

// --------------------------------------------------- per-row + segment reduce
__global__ __launch_bounds__(256) void reduce_rows(const float* __restrict__ wsT,
                                                   const int* __restrict__ labels,
                                                   float* __restrict__ part) {
    __shared__ float Tb[NUM_LABELS];
    const int tid = threadIdx.x;
    if (tid < NUM_LABELS) Tb[tid] = 0.f;
    __syncthreads();
    const int row = blockIdx.x * 256 + tid;
    float t = 0.f;
    #pragma unroll
    for (int p = 0; p < NPAN; ++p) t += wsT[(size_t)p * N_EMB + row];
    atomicAdd(&Tb[labels[row]], t);
    __syncthreads();
    if (tid < NUM_LABELS) part[blockIdx.x * NUM_LABELS + tid] = Tb[tid];
}

// ----------------------------------------------------------------- finalize
__global__ __launch_bounds__(128) void finalize_kernel(const float* __restrict__ part,
                                                       const float* __restrict__ Acorr,
                                                       const float* __restrict__ Pcorr,
                                                       const int* __restrict__ cnt,
                                                       float* __restrict__ out) {
    const int g = threadIdx.x;   // label id
    float T = 0.f;
    #pragma unroll 8
    for (int b = 0; b < 32; ++b) T += part[b * NUM_LABELS + g];
    const float B = T - Pcorr[g];
    float v = (cnt[g] >= 2) ? Acorr[g] * B : 0.f;
    #pragma unroll
    for (int off = 32; off >= 1; off >>= 1) v += __shfl_xor(v, off);
    __shared__ float w2[2];
    if ((g & 63) == 0) w2[g >> 6] = v;
    __syncthreads();
    if (g == 0) out[0] = logf(1.0f + w2[0] + w2[1]);
}

// ------------------------------------------------------------------ launcher
extern "C" void kernel_launch(void* const* d_in, const int* in_sizes, int n_in,
                              void* d_out, int out_size, void* d_ws, size_t ws_size,
                              hipStream_t stream) {
    const float* emb    = (const float*)d_in[0];
    const int*   labels = (const int*)d_in[1];
    const float* scale  = (const float*)d_in[2];
    float* out = (float*)d_out;

    char* base = (char*)d_ws;
    char*     e8    = base;                        // 2 MB (superfrag fp8, prescaled)
    unsigned* e16   = (unsigned*)(base + (2u << 20));        // 4 MB bf16 row-major
    float*    wsT   = (float*)(base + (6u << 20));           // 2 MB
    int*      cnt   = (int*)(base + (8u << 20));             // 512 B
    int*      perm  = (int*)(base + (8u << 20) + 1024);      // 96 KB
    float*    Acorr = (float*)(base + (8u << 20) + 112 * 1024);
    float*    Pcorr = Acorr + NUM_LABELS;
    float*    part  = Pcorr + NUM_LABELS;                    // 16 KB

    normalize_kernel<<<N_EMB / 4, 256, 0, stream>>>(emb, scale, e8, e16, cnt);
    build_lists<<<N_EMB / 256, 256, 0, stream>>>(labels, cnt, perm);
    cosent_main<<<NTRI + NUM_LABELS, 256, 0, stream>>>(e8, (const __bf16*)e16, perm,
                                                       cnt, scale, wsT, Acorr, Pcorr);
    reduce_rows<<<N_EMB / 256, 256, 0, stream>>>(wsT, labels, part);
    finalize_kernel<<<1, 128, 0, stream>>>(part, Acorr, Pcorr, cnt, out);
}

// Round 13
// 47.796 us; speedup vs baseline: 1.3658x; 1.3658x over previous
//
#include <hip/hip_runtime.h>
#include <hip/hip_bf16.h>
#include <math.h>

// CoSent clustering loss on MI355X — round 13.
// Revert to r10 (best, 47.1us) + targeted fixes:
//  * reduce_rows: 32 -> 128 blocks, coalesced panel-major reads (16/thread),
//    fused label binning + counts (the old version was latency-bound on 64
//    strided loads at 1/8 CU utilization — est. 8-15us).
//  * main: closed-form triangular decode; fp8 prescaled by sqrt(s*log2e) so
//    the epilogue is exp2(acc) directly (no per-element multiply).

typedef __attribute__((ext_vector_type(2))) long l2;     // two fp8 frags
typedef __attribute__((ext_vector_type(4))) float f32x4;

#define N_EMB 8192
#define D_EMB 256
#define NUM_LABELS 128
#define PAN 128
#define NPAN (N_EMB / PAN)           // 64
#define NTRI (NPAN * (NPAN + 1) / 2) // 2080 = 8 * 260

// ---- DPP 16-lane reduction helpers ----
template <int CTRL>
__device__ __forceinline__ float dpp_add(float x) {
    int y = __builtin_amdgcn_update_dpp(0, __builtin_bit_cast(int, x),
                                        CTRL, 0xF, 0xF, false);
    return x + __builtin_bit_cast(float, y);
}
__device__ __forceinline__ float red16(float x) {
    x = dpp_add<0xB1>(x);    // quad_perm xor1
    x = dpp_add<0x4E>(x);    // quad_perm xor2
    x = dpp_add<0x124>(x);   // row_ror:4
    x = dpp_add<0x128>(x);   // row_ror:8
    return x;
}

__device__ __forceinline__ float exp2hw(float x) {
    float r;
    asm("v_exp_f32 %0, %1" : "=v"(r) : "v"(x));
    return r;
}

__device__ __forceinline__ unsigned packbf(float a, float b) {
    unsigned ua = __builtin_bit_cast(unsigned, a);
    unsigned ub = __builtin_bit_cast(unsigned, b);
    ua += 0x7FFFu + ((ua >> 16) & 1u);   // RTNE to bf16
    ub += 0x7FFFu + ((ub >> 16) & 1u);
    return (ua >> 16) | (ub & 0xFFFF0000u);
}

// ---------------------------------------------------------------- normalize
// Emits fp8 superfrag-major, PRESCALED by sqrt(s*log2e): MFMA acc is then
// s*log2e*sim and the epilogue is a bare exp2. Layout per r10.
__global__ __launch_bounds__(256) void normalize_kernel(const float* __restrict__ emb,
                                                        const float* __restrict__ scale,
                                                        char* __restrict__ e8) {
    const int wid = threadIdx.x >> 6, lane = threadIdx.x & 63;
    const int row = blockIdx.x * 4 + wid;
    const f32x4 x = *(const f32x4*)(emb + (size_t)row * D_EMB + lane * 4);
    float ss = x[0]*x[0] + x[1]*x[1] + x[2]*x[2] + x[3]*x[3];
    #pragma unroll
    for (int off = 32; off >= 1; off >>= 1) ss += __shfl_xor(ss, off);
    const float r = 1.0f / fmaxf(sqrtf(ss), 1e-12f);
    const float ps = sqrtf(scale[0] * 1.44269504088896f) * r;
    int v = __builtin_amdgcn_cvt_pk_fp8_f32(x[0] * ps, x[1] * ps, 0, false);
    v = __builtin_amdgcn_cvt_pk_fp8_f32(x[2] * ps, x[3] * ps, v, true);
    const int u    = lane >> 4;
    const int half = (lane >> 3) & 1;
    const int lp   = ((lane >> 1) & 3) * 16 + (row & 15);
    const int j0   = (lane & 1) * 4;
    char* dst = e8 + ((size_t)(row >> 4) * 4 + u) * 1024 + lp * 16 + half * 8 + j0;
    *(unsigned*)dst = (unsigned)v;
}

// ---- pinned coalesced superfrag load: SGPR base + VGPR offset + literal ----
#define LOADF(dst, voff, sb, OFFSTR) \
    asm volatile("global_load_dwordx4 %0, %1, %2 offset:" OFFSTR \
                 : "=v"(dst) : "v"(voff), "s"(sb))

#define ISSUE(PA_, PB_, OFFSTR) \
    LOADF(PA_[0], voA[0], sbA, OFFSTR); LOADF(PA_[1], voA[1], sbA, OFFSTR); \
    LOADF(PA_[2], voA[2], sbA, OFFSTR); LOADF(PA_[3], voA[3], sbA, OFFSTR); \
    LOADF(PB_[0], voB[0], sbB, OFFSTR); LOADF(PB_[1], voB[1], sbB, OFFSTR); \
    LOADF(PB_[2], voB[2], sbB, OFFSTR); LOADF(PB_[3], voB[3], sbB, OFFSTR)

#define WAITV(NSTR) \
    asm volatile("s_waitcnt vmcnt(" NSTR ")" ::: "memory"); \
    __builtin_amdgcn_sched_barrier(0)

#define MF8(a, b, c) __builtin_amdgcn_mfma_f32_16x16x32_fp8_fp8(a, b, c, 0, 0, 0)

#define MROW(PA_, PB_, mi, H) \
    acc[mi][0] = MF8(PA_[mi][H], PB_[0][H], acc[mi][0]); \
    acc[mi][1] = MF8(PA_[mi][H], PB_[1][H], acc[mi][1]); \
    acc[mi][2] = MF8(PA_[mi][H], PB_[2][H], acc[mi][2]); \
    acc[mi][3] = MF8(PA_[mi][H], PB_[3][H], acc[mi][3]);

#define MFMA32(PA_, PB_) \
    __builtin_amdgcn_s_setprio(1); \
    MROW(PA_, PB_, 0, 0) MROW(PA_, PB_, 1, 0) MROW(PA_, PB_, 2, 0) MROW(PA_, PB_, 3, 0) \
    MROW(PA_, PB_, 0, 1) MROW(PA_, PB_, 1, 1) MROW(PA_, PB_, 2, 1) MROW(PA_, PB_, 3, 1) \
    __builtin_amdgcn_s_setprio(0)

// ----------------------------------------------------------------- main GEMM
__global__ __launch_bounds__(256, 3) void cosent_main(const char* __restrict__ e8,
                                                      const int* __restrict__ labels,
                                                      unsigned* __restrict__ wsAB) {
    __shared__ float rowsc[2][PAN][2];
    __shared__ float colsc[2][PAN][2];
    __shared__ int labR[PAN], labC[PAN];

    // XCD-bijective swizzle (2080 = 8*260) + closed-form triangular decode.
    const int bid = blockIdx.x;
    const int swz = (bid & 7) * 260 + (bid >> 3);
    int by = (int)((129.0f - sqrtf(16641.0f - 8.0f * (float)swz)) * 0.5f);
    by = by < 0 ? 0 : (by > 63 ? 63 : by);
    while (by < 63 && (by + 1) * (129 - (by + 1)) / 2 <= swz) ++by;
    while (by > 0 && by * (129 - by) / 2 > swz) --by;
    const int bx = by + (swz - by * (129 - by) / 2);
    const bool diag = (bx == by);
    const int rowBase = by * PAN, colBase = bx * PAN;

    const int tid = threadIdx.x, lane = tid & 63, wid = tid >> 6;
    const int wm = wid >> 1, wn = wid & 1;
    const int rr = lane & 15, kh = lane >> 4;

    if (tid < PAN) labR[tid] = labels[rowBase + tid];
    else           labC[tid - PAN] = labels[colBase + tid - PAN];

    // per-frag-group voffsets (bytes): group (w*4+i) stride 4096, lane 16B
    const int laneB = lane * 16;
    int voA[4], voB[4];
    #pragma unroll
    for (int i = 0; i < 4; ++i) {
        voA[i] = (wm * 4 + i) * 4096 + laneB;
        voB[i] = (wn * 4 + i) * 4096 + laneB;
    }
    const char* sbA = e8 + (size_t)rowBase * 256;
    const char* sbB = e8 + (size_t)colBase * 256;

    f32x4 acc[4][4];
    #pragma unroll
    for (int i = 0; i < 4; ++i)
        #pragma unroll
        for (int j = 0; j < 4; ++j) acc[i][j] = (f32x4){0.f, 0.f, 0.f, 0.f};

    l2 pA[4], pB[4], qA[4], qB[4];

    ISSUE(pA, pB, "0");                                   // u=0
    ISSUE(qA, qB, "1024"); WAITV("8"); MFMA32(pA, pB);    // u=1 | u0
    ISSUE(pA, pB, "2048"); WAITV("8"); MFMA32(qA, qB);    // u=2 | u1
    ISSUE(qA, qB, "3072"); WAITV("8"); MFMA32(pA, pB);    // u=3 | u2
    WAITV("0"); MFMA32(qA, qB);                           //     | u3

    __syncthreads();   // labels visible (K-loop has no LDS dependence)

    // ------------- fused epilogue: acc is already s*log2e*sim
    int lc[4];
    #pragma unroll
    for (int ni = 0; ni < 4; ++ni) lc[ni] = labC[wn * 64 + ni * 16 + rr];
    float colA[4] = {0.f, 0.f, 0.f, 0.f}, colB[4] = {0.f, 0.f, 0.f, 0.f};

    #pragma unroll
    for (int mi = 0; mi < 4; ++mi) {
        #pragma unroll
        for (int r = 0; r < 4; ++r) {
            const int rowL = wm * 64 + mi * 16 + kh * 4 + r;
            const int lr = labR[rowL];
            float asum = 0.f, bsum = 0.f;
            #pragma unroll
            for (int ni = 0; ni < 4; ++ni) {
                const int colL = wn * 64 + ni * 16 + rr;
                const float val = acc[mi][ni][r];
                const bool pos = (lr == lc[ni]);
                float ex = exp2hw(pos ? -val : val);
                if (diag && rowL == colL) ex = 0.f;   // exclude self-pairs
                if (pos) { asum += ex; colA[ni] += ex; }
                else     { bsum += ex; colB[ni] += ex; }
            }
            asum = red16(asum);
            bsum = red16(bsum);
            if (rr == 0) { rowsc[wn][rowL][0] = asum; rowsc[wn][rowL][1] = bsum; }
        }
    }

    if (!diag) {   // col-side (transposed contribution via symmetry)
        #pragma unroll
        for (int ni = 0; ni < 4; ++ni) {
            float a = colA[ni], b = colB[ni];
            a += __shfl_xor(a, 16); a += __shfl_xor(a, 32);
            b += __shfl_xor(b, 16); b += __shfl_xor(b, 32);
            if (lane < 16) {
                colsc[wm][wn * 64 + ni * 16 + lane][0] = a;
                colsc[wm][wn * 64 + ni * 16 + lane][1] = b;
            }
        }
    }
    __syncthreads();

    if (tid < PAN) {
        const float ra = rowsc[0][tid][0] + rowsc[1][tid][0];
        const float rb = rowsc[0][tid][1] + rowsc[1][tid][1];
        wsAB[(size_t)bx * N_EMB + rowBase + tid] = packbf(ra, rb);
        if (!diag) {
            const float ca = colsc[0][tid][0] + colsc[1][tid][0];
            const float cb = colsc[0][tid][1] + colsc[1][tid][1];
            wsAB[(size_t)by * N_EMB + colBase + tid] = packbf(ca, cb);
        }
    }
}

// ----------------------------------------------- coalesced reduce + label bin
// 128 blocks x 64 rows. Wave w reads panels w*16..w*16+15 for all 64 rows
// (consecutive lanes -> consecutive rows: fully coalesced). LDS combine,
// label binning + count, per-block partial out.
__global__ __launch_bounds__(256) void reduce_rows(const unsigned* __restrict__ wsAB,
                                                   const int* __restrict__ labels,
                                                   float* __restrict__ part) {
    __shared__ float sA[4][64], sB[4][64];
    __shared__ float binA[NUM_LABELS], binB[NUM_LABELS];
    __shared__ int binC[NUM_LABELS];
    const int tid = threadIdx.x, lane = tid & 63, wid = tid >> 6;
    if (tid < NUM_LABELS) { binA[tid] = 0.f; binB[tid] = 0.f; binC[tid] = 0; }
    const int rowBase = blockIdx.x * 64;
    float a = 0.f, b = 0.f;
    #pragma unroll
    for (int p = 0; p < 16; ++p) {
        const unsigned u = wsAB[(size_t)(wid * 16 + p) * N_EMB + rowBase + lane];
        a += __builtin_bit_cast(float, u << 16);
        b += __builtin_bit_cast(float, u & 0xFFFF0000u);
    }
    sA[wid][lane] = a; sB[wid][lane] = b;
    __syncthreads();
    if (tid < 64) {
        const float A = sA[0][tid] + sA[1][tid] + sA[2][tid] + sA[3][tid];
        const float B = sB[0][tid] + sB[1][tid] + sB[2][tid] + sB[3][tid];
        const int l = labels[rowBase + tid];
        atomicAdd(&binA[l], A);
        atomicAdd(&binB[l], B);
        atomicAdd(&binC[l], 1);
    }
    __syncthreads();
    if (tid < NUM_LABELS) {
        float* p = part + ((size_t)blockIdx.x * NUM_LABELS + tid) * 3;
        p[0] = binA[tid]; p[1] = binB[tid]; p[2] = (float)binC[tid];
    }
}

// ----------------------------------------------------------------- finalize
__global__ __launch_bounds__(128) void finalize_kernel(const float* __restrict__ part,
                                                       float* __restrict__ out) {
    const int g = threadIdx.x;   // label id
    float A = 0.f, B = 0.f, c = 0.f;
    #pragma unroll 8
    for (int b = 0; b < 128; ++b) {
        const float* p = part + ((size_t)b * NUM_LABELS + g) * 3;
        A += p[0]; B += p[1]; c += p[2];
    }
    float v = (c >= 2.f) ? A * B : 0.f;
    #pragma unroll
    for (int off = 32; off >= 1; off >>= 1) v += __shfl_xor(v, off);
    __shared__ float w2[2];
    if ((g & 63) == 0) w2[g >> 6] = v;
    __syncthreads();
    if (g == 0) out[0] = logf(1.0f + w2[0] + w2[1]);
}

// ------------------------------------------------------------------ launcher
extern "C" void kernel_launch(void* const* d_in, const int* in_sizes, int n_in,
                              void* d_out, int out_size, void* d_ws, size_t ws_size,
                              hipStream_t stream) {
    const float* emb    = (const float*)d_in[0];
    const int*   labels = (const int*)d_in[1];
    const float* scale  = (const float*)d_in[2];
    float* out = (float*)d_out;

    char* base = (char*)d_ws;
    char*     e8   = base;                                   // 2 MB (superfrag fp8, prescaled)
    unsigned* wsAB = (unsigned*)(base + (2u << 20));         // 2 MB
    float*    part = (float*)(base + (4u << 20));            // 192 KB

    normalize_kernel<<<N_EMB / 4, 256, 0, stream>>>(emb, scale, e8);
    cosent_main<<<NTRI, 256, 0, stream>>>(e8, labels, wsAB);
    reduce_rows<<<NUM_LABELS, 256, 0, stream>>>(wsAB, labels, part);
    finalize_kernel<<<1, 128, 0, stream>>>(part, out);
}

// Round 15
// 47.777 us; speedup vs baseline: 1.3663x; 1.0004x over previous
//
#include <hip/hip_runtime.h>
#include <hip/hip_bf16.h>
#include <math.h>

// CoSent clustering loss on MI355X — round 15.
// r13's deterministic pipeline (NO float atomics on the output path — r14's
// global atomicAdd made the result run-to-run nondeterministic and tripped
// the harness) + r14's main-kernel prologue hoist: the first two ISSUE
// bursts go out before label staging / acc-init, filling ~150cy of the first
// L2 latency.

typedef __attribute__((ext_vector_type(2))) long l2;     // two fp8 frags
typedef __attribute__((ext_vector_type(4))) float f32x4;

#define N_EMB 8192
#define D_EMB 256
#define NUM_LABELS 128
#define PAN 128
#define NPAN (N_EMB / PAN)           // 64
#define NTRI (NPAN * (NPAN + 1) / 2) // 2080 = 8 * 260

// ---- DPP 16-lane reduction helpers ----
template <int CTRL>
__device__ __forceinline__ float dpp_add(float x) {
    int y = __builtin_amdgcn_update_dpp(0, __builtin_bit_cast(int, x),
                                        CTRL, 0xF, 0xF, false);
    return x + __builtin_bit_cast(float, y);
}
__device__ __forceinline__ float red16(float x) {
    x = dpp_add<0xB1>(x);    // quad_perm xor1
    x = dpp_add<0x4E>(x);    // quad_perm xor2
    x = dpp_add<0x124>(x);   // row_ror:4
    x = dpp_add<0x128>(x);   // row_ror:8
    return x;
}

__device__ __forceinline__ float exp2hw(float x) {
    float r;
    asm("v_exp_f32 %0, %1" : "=v"(r) : "v"(x));
    return r;
}

__device__ __forceinline__ unsigned packbf(float a, float b) {
    unsigned ua = __builtin_bit_cast(unsigned, a);
    unsigned ub = __builtin_bit_cast(unsigned, b);
    ua += 0x7FFFu + ((ua >> 16) & 1u);   // RTNE to bf16
    ub += 0x7FFFu + ((ub >> 16) & 1u);
    return (ua >> 16) | (ub & 0xFFFF0000u);
}

// ---------------------------------------------------------------- normalize
// fp8 superfrag-major, PRESCALED by sqrt(s*log2e): MFMA acc = s*log2e*sim,
// epilogue is a bare exp2. Layout per r10.
__global__ __launch_bounds__(256) void normalize_kernel(const float* __restrict__ emb,
                                                        const float* __restrict__ scale,
                                                        char* __restrict__ e8) {
    const int wid = threadIdx.x >> 6, lane = threadIdx.x & 63;
    const int row = blockIdx.x * 4 + wid;
    const f32x4 x = *(const f32x4*)(emb + (size_t)row * D_EMB + lane * 4);
    float ss = x[0]*x[0] + x[1]*x[1] + x[2]*x[2] + x[3]*x[3];
    #pragma unroll
    for (int off = 32; off >= 1; off >>= 1) ss += __shfl_xor(ss, off);
    const float r = 1.0f / fmaxf(sqrtf(ss), 1e-12f);
    const float ps = sqrtf(scale[0] * 1.44269504088896f) * r;
    int v = __builtin_amdgcn_cvt_pk_fp8_f32(x[0] * ps, x[1] * ps, 0, false);
    v = __builtin_amdgcn_cvt_pk_fp8_f32(x[2] * ps, x[3] * ps, v, true);
    const int u    = lane >> 4;
    const int half = (lane >> 3) & 1;
    const int lp   = ((lane >> 1) & 3) * 16 + (row & 15);
    const int j0   = (lane & 1) * 4;
    char* dst = e8 + ((size_t)(row >> 4) * 4 + u) * 1024 + lp * 16 + half * 8 + j0;
    *(unsigned*)dst = (unsigned)v;
}

// ---- pinned coalesced superfrag load: SGPR base + VGPR offset + literal ----
#define LOADF(dst, voff, sb, OFFSTR) \
    asm volatile("global_load_dwordx4 %0, %1, %2 offset:" OFFSTR \
                 : "=v"(dst) : "v"(voff), "s"(sb))

#define ISSUE(PA_, PB_, OFFSTR) \
    LOADF(PA_[0], voA[0], sbA, OFFSTR); LOADF(PA_[1], voA[1], sbA, OFFSTR); \
    LOADF(PA_[2], voA[2], sbA, OFFSTR); LOADF(PA_[3], voA[3], sbA, OFFSTR); \
    LOADF(PB_[0], voB[0], sbB, OFFSTR); LOADF(PB_[1], voB[1], sbB, OFFSTR); \
    LOADF(PB_[2], voB[2], sbB, OFFSTR); LOADF(PB_[3], voB[3], sbB, OFFSTR)

#define WAITV(NSTR) \
    asm volatile("s_waitcnt vmcnt(" NSTR ")" ::: "memory"); \
    __builtin_amdgcn_sched_barrier(0)

#define MF8(a, b, c) __builtin_amdgcn_mfma_f32_16x16x32_fp8_fp8(a, b, c, 0, 0, 0)

#define MROW(PA_, PB_, mi, H) \
    acc[mi][0] = MF8(PA_[mi][H], PB_[0][H], acc[mi][0]); \
    acc[mi][1] = MF8(PA_[mi][H], PB_[1][H], acc[mi][1]); \
    acc[mi][2] = MF8(PA_[mi][H], PB_[2][H], acc[mi][2]); \
    acc[mi][3] = MF8(PA_[mi][H], PB_[3][H], acc[mi][3]);

#define MFMA32(PA_, PB_) \
    __builtin_amdgcn_s_setprio(1); \
    MROW(PA_, PB_, 0, 0) MROW(PA_, PB_, 1, 0) MROW(PA_, PB_, 2, 0) MROW(PA_, PB_, 3, 0) \
    MROW(PA_, PB_, 0, 1) MROW(PA_, PB_, 1, 1) MROW(PA_, PB_, 2, 1) MROW(PA_, PB_, 3, 1) \
    __builtin_amdgcn_s_setprio(0)

// ----------------------------------------------------------------- main GEMM
__global__ __launch_bounds__(256, 3) void cosent_main(const char* __restrict__ e8,
                                                      const int* __restrict__ labels,
                                                      unsigned* __restrict__ wsAB) {
    __shared__ float rowsc[2][PAN][2];
    __shared__ float colsc[2][PAN][2];
    __shared__ int labR[PAN], labC[PAN];

    // XCD-bijective swizzle (2080 = 8*260) + closed-form triangular decode.
    const int bid = blockIdx.x;
    const int swz = (bid & 7) * 260 + (bid >> 3);
    int by = (int)((129.0f - sqrtf(16641.0f - 8.0f * (float)swz)) * 0.5f);
    by = by < 0 ? 0 : (by > 63 ? 63 : by);
    while (by < 63 && (by + 1) * (129 - (by + 1)) / 2 <= swz) ++by;
    while (by > 0 && by * (129 - by) / 2 > swz) --by;
    const int bx = by + (swz - by * (129 - by) / 2);
    const bool diag = (bx == by);
    const int rowBase = by * PAN, colBase = bx * PAN;

    const int tid = threadIdx.x, lane = tid & 63, wid = tid >> 6;
    const int wm = wid >> 1, wn = wid & 1;
    const int rr = lane & 15, kh = lane >> 4;

    // ---- addresses + first two ISSUE bursts (earliest possible; volatile
    // asm placement is the schedule — fills the first L2 latency with the
    // label staging + acc init below)
    const int laneB = lane * 16;
    int voA[4], voB[4];
    #pragma unroll
    for (int i = 0; i < 4; ++i) {
        voA[i] = (wm * 4 + i) * 4096 + laneB;
        voB[i] = (wn * 4 + i) * 4096 + laneB;
    }
    const char* sbA = e8 + (size_t)rowBase * 256;
    const char* sbB = e8 + (size_t)colBase * 256;

    l2 pA[4], pB[4], qA[4], qB[4];
    ISSUE(pA, pB, "0");                                   // u=0 in flight
    ISSUE(qA, qB, "1024");                                // u=1 in flight

    // latency-fill work: label staging + acc init
    if (tid < PAN) labR[tid] = labels[rowBase + tid];
    else           labC[tid - PAN] = labels[colBase + tid - PAN];

    f32x4 acc[4][4];
    #pragma unroll
    for (int i = 0; i < 4; ++i)
        #pragma unroll
        for (int j = 0; j < 4; ++j) acc[i][j] = (f32x4){0.f, 0.f, 0.f, 0.f};

    WAITV("8"); MFMA32(pA, pB);                           // u0
    ISSUE(pA, pB, "2048"); WAITV("8"); MFMA32(qA, qB);    // u=2 | u1
    ISSUE(qA, qB, "3072"); WAITV("8"); MFMA32(pA, pB);    // u=3 | u2
    WAITV("0"); MFMA32(qA, qB);                           //     | u3

    __syncthreads();   // labels visible

    // ------------- fused epilogue: acc is already s*log2e*sim
    int lc[4];
    #pragma unroll
    for (int ni = 0; ni < 4; ++ni) lc[ni] = labC[wn * 64 + ni * 16 + rr];
    float colA[4] = {0.f, 0.f, 0.f, 0.f}, colB[4] = {0.f, 0.f, 0.f, 0.f};

    #pragma unroll
    for (int mi = 0; mi < 4; ++mi) {
        #pragma unroll
        for (int r = 0; r < 4; ++r) {
            const int rowL = wm * 64 + mi * 16 + kh * 4 + r;
            const int lr = labR[rowL];
            float asum = 0.f, bsum = 0.f;
            #pragma unroll
            for (int ni = 0; ni < 4; ++ni) {
                const int colL = wn * 64 + ni * 16 + rr;
                const float val = acc[mi][ni][r];
                const bool pos = (lr == lc[ni]);
                float ex = exp2hw(pos ? -val : val);
                if (diag && rowL == colL) ex = 0.f;   // exclude self-pairs
                if (pos) { asum += ex; colA[ni] += ex; }
                else     { bsum += ex; colB[ni] += ex; }
            }
            asum = red16(asum);
            bsum = red16(bsum);
            if (rr == 0) { rowsc[wn][rowL][0] = asum; rowsc[wn][rowL][1] = bsum; }
        }
    }

    if (!diag) {   // col-side (transposed contribution via symmetry)
        #pragma unroll
        for (int ni = 0; ni < 4; ++ni) {
            float a = colA[ni], b = colB[ni];
            a += __shfl_xor(a, 16); a += __shfl_xor(a, 32);
            b += __shfl_xor(b, 16); b += __shfl_xor(b, 32);
            if (lane < 16) {
                colsc[wm][wn * 64 + ni * 16 + lane][0] = a;
                colsc[wm][wn * 64 + ni * 16 + lane][1] = b;
            }
        }
    }
    __syncthreads();

    if (tid < PAN) {
        const float ra = rowsc[0][tid][0] + rowsc[1][tid][0];
        const float rb = rowsc[0][tid][1] + rowsc[1][tid][1];
        wsAB[(size_t)bx * N_EMB + rowBase + tid] = packbf(ra, rb);
        if (!diag) {
            const float ca = colsc[0][tid][0] + colsc[1][tid][0];
            const float cb = colsc[0][tid][1] + colsc[1][tid][1];
            wsAB[(size_t)by * N_EMB + colBase + tid] = packbf(ca, cb);
        }
    }
}

// ----------------------------------------------- coalesced reduce + label bin
// 128 blocks x 64 rows; fully-coalesced panel reads; LDS label bins (LDS
// atomics are deterministic ONLY in count, so sums also go through a fixed
// per-block partial -> deterministic finalize order).
__global__ __launch_bounds__(256) void reduce_rows(const unsigned* __restrict__ wsAB,
                                                   const int* __restrict__ labels,
                                                   float* __restrict__ part) {
    __shared__ float sA[4][64], sB[4][64];
    __shared__ float binA[NUM_LABELS], binB[NUM_LABELS];
    __shared__ int binC[NUM_LABELS];
    const int tid = threadIdx.x, lane = tid & 63, wid = tid >> 6;
    if (tid < NUM_LABELS) { binA[tid] = 0.f; binB[tid] = 0.f; binC[tid] = 0; }
    const int rowBase = blockIdx.x * 64;
    float a = 0.f, b = 0.f;
    #pragma unroll
    for (int p = 0; p < 16; ++p) {
        const unsigned u = wsAB[(size_t)(wid * 16 + p) * N_EMB + rowBase + lane];
        a += __builtin_bit_cast(float, u << 16);
        b += __builtin_bit_cast(float, u & 0xFFFF0000u);
    }
    sA[wid][lane] = a; sB[wid][lane] = b;
    __syncthreads();
    if (tid < 64) {   // serial per-row order within the block -> deterministic
        const float A = sA[0][tid] + sA[1][tid] + sA[2][tid] + sA[3][tid];
        const float B = sB[0][tid] + sB[1][tid] + sB[2][tid] + sB[3][tid];
        const int l = labels[rowBase + tid];
        atomicAdd(&binA[l], A);
        atomicAdd(&binB[l], B);
        atomicAdd(&binC[l], 1);
    }
    __syncthreads();
    if (tid < NUM_LABELS) {
        float* p = part + ((size_t)blockIdx.x * NUM_LABELS + tid) * 3;
        p[0] = binA[tid]; p[1] = binB[tid]; p[2] = (float)binC[tid];
    }
}

// ----------------------------------------------------------------- finalize
__global__ __launch_bounds__(128) void finalize_kernel(const float* __restrict__ part,
                                                       float* __restrict__ out) {
    const int g = threadIdx.x;   // label id
    float A = 0.f, B = 0.f, c = 0.f;
    #pragma unroll 8
    for (int b = 0; b < 128; ++b) {   // fixed order -> deterministic
        const float* p = part + ((size_t)b * NUM_LABELS + g) * 3;
        A += p[0]; B += p[1]; c += p[2];
    }
    float v = (c >= 2.f) ? A * B : 0.f;
    #pragma unroll
    for (int off = 32; off >= 1; off >>= 1) v += __shfl_xor(v, off);
    __shared__ float w2[2];
    if ((g & 63) == 0) w2[g >> 6] = v;
    __syncthreads();
    if (g == 0) out[0] = logf(1.0f + w2[0] + w2[1]);
}

// ------------------------------------------------------------------ launcher
extern "C" void kernel_launch(void* const* d_in, const int* in_sizes, int n_in,
                              void* d_out, int out_size, void* d_ws, size_t ws_size,
                              hipStream_t stream) {
    const float* emb    = (const float*)d_in[0];
    const int*   labels = (const int*)d_in[1];
    const float* scale  = (const float*)d_in[2];
    float* out = (float*)d_out;

    char* base = (char*)d_ws;
    char*     e8   = base;                                   // 2 MB (superfrag fp8, prescaled)
    unsigned* wsAB = (unsigned*)(base + (2u << 20));         // 2 MB
    float*    part = (float*)(base + (4u << 20));            // 192 KB

    normalize_kernel<<<N_EMB / 4, 256, 0, stream>>>(emb, scale, e8);
    cosent_main<<<NTRI, 256, 0, stream>>>(e8, labels, wsAB);
    reduce_rows<<<NUM_LABELS, 256, 0, stream>>>(wsAB, labels, part);
    finalize_kernel<<<1, 128, 0, stream>>>(part, out);
}